// Round 6
// baseline (185.942 us; speedup 1.0000x reference)
//
#include <hip/hip_runtime.h>
#include <hip/hip_bf16.h>

#define D   768
#define D2  384      // fp4 row bytes
#define NQ  16       // q groups
#define NP  128      // p groups
#define QI  64       // q vectors per group
#define PJ  256      // p vectors per group
#define MQ  (NQ*QI)  // 1024 query vectors
#define MP  (NP*PJ)  // 32768 passage vectors
#define NROWBLK ((MP + MQ) / 4)   // norm blocks (4 rows each)

typedef __attribute__((ext_vector_type(8)))  int   int8v;     // f8f6f4 operand
typedef __attribute__((ext_vector_type(16))) float floatx16;  // 32x32 MFMA acc

#define LDS_AS __attribute__((address_space(3)))
#define GLB_AS __attribute__((address_space(1)))

// async global->LDS DMA, 16 B/lane; LDS dest = (wave-uniform) base + lane*16
static __device__ __forceinline__ void async_copy16(const uchar* g, uchar* l) {
    __builtin_amdgcn_global_load_lds((const GLB_AS uint32_t*)g,
                                     (LDS_AS uint32_t*)l, 16, 0, 0);
}

// encode float4 (already L2-normalized via inv) as 4x fp4 e2m1 nibbles of x*16.
// grid {0,.5,1,1.5,2,3,4,6}: codes 0..4 are uniform step .5 -> rint(2y); 5..7 by cmp.
static __device__ __forceinline__ uint enc4(float4 v, float inv) {
    uint r = 0;
    const float* f = (const float*)&v;
    #pragma unroll
    for (int i = 0; i < 4; i++) {
        float x = f[i] * inv;
        float y = fabsf(x) * 16.0f;
        uint c;
        if (y < 2.25f) c = (uint)(int)rintf(y + y);
        else           c = y < 3.5f ? 5u : (y < 5.0f ? 6u : 7u);
        c |= (__float_as_uint(x) >> 28) & 8u;    // sign
        r |= c << (4 * i);
    }
    return r;
}

// ---------------------------------------------------------------------------
// Kernel 1: fused (a) L2-normalize fp32 -> fp4 e2m1 (x*16 grid) for both
// inputs, one row per wave; (b) scores[q][p] = dot(q_hidden[q,0], p_hidden[p,0])
// on the trailing 512 blocks (independent work, saves a launch).
// ---------------------------------------------------------------------------
__global__ __launch_bounds__(256) void norm_scores(const float* __restrict__ ph,
                                                   const float* __restrict__ qh,
                                                   uchar* __restrict__ P4,
                                                   uchar* __restrict__ Q4,
                                                   float* __restrict__ scores) {
    const int wave = threadIdx.x >> 6, lane = threadIdx.x & 63;
    if (blockIdx.x < NROWBLK) {
        int row = blockIdx.x * 4 + wave;
        const float* in; uchar* out;
        if (row < MP) { in = ph; out = P4; }
        else          { in = qh; out = Q4; row -= MP; }
        const float4* r4 = (const float4*)(in + (size_t)row * D);

        float4 x0 = r4[lane], x1 = r4[lane + 64], x2 = r4[lane + 128];
        float ss = x0.x*x0.x + x0.y*x0.y + x0.z*x0.z + x0.w*x0.w
                 + x1.x*x1.x + x1.y*x1.y + x1.z*x1.z + x1.w*x1.w
                 + x2.x*x2.x + x2.y*x2.y + x2.z*x2.z + x2.w*x2.w;
        #pragma unroll
        for (int o = 32; o > 0; o >>= 1) ss += __shfl_xor(ss, o, 64);
        float inv = 1.0f / fmaxf(sqrtf(ss), 1e-12f);

        ushort* o2 = (ushort*)(out + (size_t)row * D2);
        o2[lane]       = (ushort)enc4(x0, inv);
        o2[lane + 64]  = (ushort)enc4(x1, inv);
        o2[lane + 128] = (ushort)enc4(x2, inv);
    } else {
        const int bid = (blockIdx.x - NROWBLK) * 4 + wave;   // 0..2047
        const int q = bid >> 7, p = bid & 127;
        const float4* qr = (const float4*)(qh + (size_t)q * QI * D);
        const float4* pr = (const float4*)(ph + (size_t)p * PJ * D);
        float s = 0.f;
        #pragma unroll
        for (int k = 0; k < 3; k++) {
            float4 a = qr[lane + k * 64], b = pr[lane + k * 64];
            s += a.x * b.x + a.y * b.y + a.z * b.z + a.w * b.w;
        }
        #pragma unroll
        for (int o = 32; o > 0; o >>= 1) s += __shfl_xor(s, o, 64);
        if (lane == 0) scores[q * NP + p] = s;
    }
}

// ---------------------------------------------------------------------------
// Kernel 2: block = 64 Q-rows (ONE q-group) x 256 P-rows (1 p-group), 4 waves.
// Wave w covers P rows [w*64, +64): tile 64x64 via 2x2 of
// mfma_scale_f32_32x32x64_f8f6f4, FMT=fp4 (cbsz=blgp=4), scales 2^-4 (e8m0
// 123) undoing the x16 encode exactly. All 4 waves share (q,p): block max ->
// mv[q][p].  acc = 64 VGPRs -> ~120 total -> 3 waves/EU; LDS 40.5 KB -> 3
// blocks/CU (12 waves: barrier drains overlap across blocks, m114).
//
// LDS: mega-step stages K=256 (128 B/row) x 3 steps. Row segment = 8 chunks
// of 16 B, XOR swizzled (stored chunk c' = c ^ (row&7)) — byte-identical
// geometry to rounds 3-5 (measured conflict-free, fully coalesced DMA).
// ---------------------------------------------------------------------------
#define SCALE16 0x7B7B7B7Bu   // e8m0 123 = 2^-4 in every byte

static __device__ __forceinline__ int8v ld_frag4(const uchar* rowp, int off) {
    uint4 u = *(const uint4*)(rowp + off);
    int8v v;
    v[0] = u.x; v[1] = u.y; v[2] = u.z; v[3] = u.w;
    v[4] = 0;   v[5] = 0;   v[6] = 0;   v[7] = 0;   // fp4 uses regs [0:3]
    return v;
}

__global__ __launch_bounds__(256, 3) void sim_max_kernel(const uchar* __restrict__ Q4,
                                                         const uchar* __restrict__ P4,
                                                         float* __restrict__ mv) {
    const int p = blockIdx.x;   // 0..127  p-group
    const int q = blockIdx.y;   // 0..15   q-group
    __shared__ uchar lA[64 * 128];    //  8 KB
    __shared__ uchar lB[256 * 128];   // 32 KB
    __shared__ float smax[4];

    const int t = threadIdx.x;
    const int wave = t >> 6, lane = t & 63;

    // DMA lane constants (8 rows x 128 B per instruction, XOR chunk swizzle)
    const int lrow = lane >> 3;                                // 0..7
    const int dmaoff = lrow * D2 + (((lane & 7) ^ lrow) << 4); // bytes

    // read lane constants
    const int r  = lane & 31;    // operand row within 32-tile
    const int kh = lane >> 5;    // k-half of the K=64 instruction
    const int rx = r & 7;

    const uchar* Abase = Q4 + (size_t)(q * QI) * D2;
    const uchar* Bbase = P4 + (size_t)p * PJ * D2;

    floatx16 acc[2][2];
    #pragma unroll
    for (int i = 0; i < 2; i++)
        #pragma unroll
        for (int j = 0; j < 2; j++)
            #pragma unroll
            for (int e = 0; e < 16; e++) acc[i][j][e] = 0.f;

    for (int k0 = 0; k0 < D2; k0 += 128) {   // 3 mega-steps of K=256
        __syncthreads();   // previous readers done before DMA overwrites LDS
        #pragma unroll
        for (int g = 0; g < 2; g++) {   // A: rows [wave*16, +16)
            const int R0 = wave * 16 + g * 8;
            async_copy16(Abase + (size_t)R0 * D2 + k0 + dmaoff, lA + R0 * 128);
        }
        #pragma unroll
        for (int g = 0; g < 8; g++) {   // B: rows [wave*64, +64)
            const int R0 = wave * 64 + g * 8;
            async_copy16(Bbase + (size_t)R0 * D2 + k0 + dmaoff, lB + R0 * 128);
        }
        __syncthreads();   // vmcnt(0) drain: DMA visible to all waves

        #pragma unroll
        for (int s = 0; s < 4; s++) {   // four K=64 substeps per mega-step
            const int off = ((s * 2 + kh) ^ rx) << 4;
            int8v a[2];
            #pragma unroll
            for (int i = 0; i < 2; i++)
                a[i] = ld_frag4(lA + (i * 32 + r) * 128, off);
            #pragma unroll
            for (int j = 0; j < 2; j++) {
                int8v b = ld_frag4(lB + (wave * 64 + j * 32 + r) * 128, off);
                #pragma unroll
                for (int i = 0; i < 2; i++)
                    acc[i][j] = __builtin_amdgcn_mfma_scale_f32_32x32x64_f8f6f4(
                        a[i], b, acc[i][j], 4, 4, 0, SCALE16, 0, SCALE16);
            }
        }
    }

    float m = -1e30f;
    #pragma unroll
    for (int i = 0; i < 2; i++)
        #pragma unroll
        for (int j = 0; j < 2; j++)
            #pragma unroll
            for (int e = 0; e < 16; e++) m = fmaxf(m, acc[i][j][e]);
    #pragma unroll
    for (int o = 32; o > 0; o >>= 1) m = fmaxf(m, __shfl_xor(m, o, 64));
    if (lane == 0) smax[wave] = m;
    __syncthreads();
    if (t == 0)
        mv[q * NP + p] = fmaxf(fmaxf(smax[0], smax[1]), fmaxf(smax[2], smax[3]));
}

// ---------------------------------------------------------------------------
// Kernel 3: final loss. One wave; lane handles columns {lane, lane+64}.
// loss = 0.5*(0.3*(CE_s + KLD_mv + CE_inter) + 0.2*(KLD_s + KLD_mv))
// (reference's CE(mv_scores) is dead code — overwritten by the KLD)
// ---------------------------------------------------------------------------
__global__ __launch_bounds__(64) void loss_kernel(const float* __restrict__ scores,
                                                  const float* __restrict__ mv,
                                                  float* __restrict__ out) {
    const int lane = threadIdx.x;
    float ce_s = 0.f, ce_t = 0.f, kld_s = 0.f, kld_m = 0.f;

    for (int q = 0; q < NQ; q++) {
        const float* srow = scores + q * NP;
        const float* mrow = mv + q * NP;
        float s0 = srow[lane], s1 = srow[lane + 64];
        float m0 = mrow[lane], m1 = mrow[lane + 64];
        float t0 = s0 + 0.3f * m0, t1 = s1 + 0.3f * m1;

        float xs = fmaxf(s0, s1), xm = fmaxf(m0, m1), xt = fmaxf(t0, t1);
        #pragma unroll
        for (int o = 32; o > 0; o >>= 1) {
            xs = fmaxf(xs, __shfl_xor(xs, o, 64));
            xm = fmaxf(xm, __shfl_xor(xm, o, 64));
            xt = fmaxf(xt, __shfl_xor(xt, o, 64));
        }
        float es = expf(s0 - xs) + expf(s1 - xs);
        float em = expf(m0 - xm) + expf(m1 - xm);
        float et = expf(t0 - xt) + expf(t1 - xt);
        #pragma unroll
        for (int o = 32; o > 0; o >>= 1) {
            es += __shfl_xor(es, o, 64);
            em += __shfl_xor(em, o, 64);
            et += __shfl_xor(et, o, 64);
        }
        float lse_s = xs + logf(es), lse_m = xm + logf(em), lse_t = xt + logf(et);

        float ls0 = s0 - lse_s, ls1 = s1 - lse_s;
        float lm0 = m0 - lse_m, lm1 = m1 - lse_m;
        float lt0 = t0 - lse_t, lt1 = t1 - lse_t;
        float pt0 = expf(lt0), pt1 = expf(lt1);
        kld_s += pt0 * (lt0 - ls0) + pt1 * (lt1 - ls1);
        kld_m += pt0 * (lt0 - lm0) + pt1 * (lt1 - lm1);

        const int tgt = q * (NP / NQ);     // q*8
        if (lane == (tgt & 63)) {
            if (tgt < 64) { ce_s -= ls0; ce_t -= lt0; }
            else          { ce_s -= ls1; ce_t -= lt1; }
        }
    }
    #pragma unroll
    for (int o = 32; o > 0; o >>= 1) {
        ce_s  += __shfl_xor(ce_s, o, 64);
        ce_t  += __shfl_xor(ce_t, o, 64);
        kld_s += __shfl_xor(kld_s, o, 64);
        kld_m += __shfl_xor(kld_m, o, 64);
    }
    if (lane == 0) {
        ce_s /= 16.f; ce_t /= 16.f; kld_s /= 16.f; kld_m /= 16.f;
        float L1 = 0.3f * (ce_s + kld_m + ce_t);
        float L2 = 0.2f * (kld_s + kld_m);
        out[0] = 0.5f * (L1 + L2);
    }
}

// ---------------------------------------------------------------------------
extern "C" void kernel_launch(void* const* d_in, const int* in_sizes, int n_in,
                              void* d_out, int out_size, void* d_ws, size_t ws_size,
                              hipStream_t stream) {
    const float* qh = (const float*)d_in[0];   // (16, 64, 768) fp32
    const float* ph = (const float*)d_in[1];   // (128, 256, 768) fp32

    // workspace layout (~13 MB): P4 fp4 | Q4 fp4 | mv f32 | scores f32
    char* ws = (char*)d_ws;
    uchar* P4 = (uchar*)ws;
    uchar* Q4 = (uchar*)(ws + (size_t)MP * D2);
    float* mv = (float*)(ws + (size_t)MP * D2 + (size_t)MQ * D2);
    float* scores = mv + NQ * NP;

    norm_scores<<<NROWBLK + 512, 256, 0, stream>>>(ph, qh, P4, Q4, scores);
    sim_max_kernel<<<dim3(NP, NQ), 256, 0, stream>>>(Q4, P4, mv);
    loss_kernel<<<1, 64, 0, stream>>>(scores, mv, (float*)d_out);
}

// Round 7
// 167.187 us; speedup vs baseline: 1.1122x; 1.1122x over previous
//
#include <hip/hip_runtime.h>
#include <hip/hip_bf16.h>

#define D   768
#define D2  384      // fp4 row bytes
#define NQ  16       // q groups
#define NP  128      // p groups
#define QI  64       // q vectors per group
#define PJ  256      // p vectors per group
#define MQ  (NQ*QI)  // 1024 query vectors
#define MP  (NP*PJ)  // 32768 passage vectors
#define NROWBLK ((MP + MQ) / 4)   // norm blocks (4 rows each)

typedef __attribute__((ext_vector_type(8)))  int   int8v;     // f8f6f4 operand
typedef __attribute__((ext_vector_type(16))) float floatx16;  // 32x32 MFMA acc

#define LDS_AS __attribute__((address_space(3)))
#define GLB_AS __attribute__((address_space(1)))

// async global->LDS DMA, 16 B/lane; LDS dest = (wave-uniform) base + lane*16
static __device__ __forceinline__ void async_copy16(const uchar* g, uchar* l) {
    __builtin_amdgcn_global_load_lds((const GLB_AS uint32_t*)g,
                                     (LDS_AS uint32_t*)l, 16, 0, 0);
}

// encode float4 (already L2-normalized via inv) as 4x fp4 e2m1 nibbles of x*16.
// grid {0,.5,1,1.5,2,3,4,6}: codes 0..4 are uniform step .5 -> rint(2y); 5..7 by cmp.
static __device__ __forceinline__ uint enc4(float4 v, float inv) {
    uint r = 0;
    const float* f = (const float*)&v;
    #pragma unroll
    for (int i = 0; i < 4; i++) {
        float x = f[i] * inv;
        float y = fabsf(x) * 16.0f;
        uint c;
        if (y < 2.25f) c = (uint)(int)rintf(y + y);
        else           c = y < 3.5f ? 5u : (y < 5.0f ? 6u : 7u);
        c |= (__float_as_uint(x) >> 28) & 8u;    // sign
        r |= c << (4 * i);
    }
    return r;
}

// ---------------------------------------------------------------------------
// Kernel 1: fused (a) L2-normalize fp32 -> fp4 e2m1 (x*16 grid) for both
// inputs, one row per wave; (b) scores[q][p] = dot(q_hidden[q,0], p_hidden[p,0])
// on the trailing 512 blocks (independent work, saves a launch).
// ---------------------------------------------------------------------------
__global__ __launch_bounds__(256) void norm_scores(const float* __restrict__ ph,
                                                   const float* __restrict__ qh,
                                                   uchar* __restrict__ P4,
                                                   uchar* __restrict__ Q4,
                                                   float* __restrict__ scores) {
    const int wave = threadIdx.x >> 6, lane = threadIdx.x & 63;
    if (blockIdx.x < NROWBLK) {
        int row = blockIdx.x * 4 + wave;
        const float* in; uchar* out;
        if (row < MP) { in = ph; out = P4; }
        else          { in = qh; out = Q4; row -= MP; }
        const float4* r4 = (const float4*)(in + (size_t)row * D);

        float4 x0 = r4[lane], x1 = r4[lane + 64], x2 = r4[lane + 128];
        float ss = x0.x*x0.x + x0.y*x0.y + x0.z*x0.z + x0.w*x0.w
                 + x1.x*x1.x + x1.y*x1.y + x1.z*x1.z + x1.w*x1.w
                 + x2.x*x2.x + x2.y*x2.y + x2.z*x2.z + x2.w*x2.w;
        #pragma unroll
        for (int o = 32; o > 0; o >>= 1) ss += __shfl_xor(ss, o, 64);
        float inv = 1.0f / fmaxf(sqrtf(ss), 1e-12f);

        ushort* o2 = (ushort*)(out + (size_t)row * D2);
        o2[lane]       = (ushort)enc4(x0, inv);
        o2[lane + 64]  = (ushort)enc4(x1, inv);
        o2[lane + 128] = (ushort)enc4(x2, inv);
    } else {
        const int bid = (blockIdx.x - NROWBLK) * 4 + wave;   // 0..2047
        const int q = bid >> 7, p = bid & 127;
        const float4* qr = (const float4*)(qh + (size_t)q * QI * D);
        const float4* pr = (const float4*)(ph + (size_t)p * PJ * D);
        float s = 0.f;
        #pragma unroll
        for (int k = 0; k < 3; k++) {
            float4 a = qr[lane + k * 64], b = pr[lane + k * 64];
            s += a.x * b.x + a.y * b.y + a.z * b.z + a.w * b.w;
        }
        #pragma unroll
        for (int o = 32; o > 0; o >>= 1) s += __shfl_xor(s, o, 64);
        if (lane == 0) scores[q * NP + p] = s;
    }
}

// ---------------------------------------------------------------------------
// Kernel 2: block = 128 Q-rows (2 q-groups) x 256 P-rows (1 p-group),
// 512 threads = 8 waves. Wave w: qi = w>>2 (q-group half), pj = w&3
// (64-wide P chunk) -> 64x64 tile via 2x2 mfma_scale_f32_32x32x64_f8f6f4,
// FMT=fp4 (cbsz=blgp=4), scales 2^-4 (e8m0 123) undoing the x16 encode.
// Same staging economics as R5 (B staged 8x) but acc = 64 VGPRs/wave ->
// 4 waves/EU -> 16 waves/CU (2 co-resident blocks): barrier drains overlap
// across blocks (m114). Per-wave DMA count 12 -> 6.
//
// LDS: mega-step stages K=256 (128 B/row) x 3 steps. Row segment = 8 chunks
// of 16 B, XOR swizzled (stored chunk c' = c ^ (row&7)) — byte-identical
// geometry to rounds 3-6 (measured conflict-free, fully coalesced DMA).
// ---------------------------------------------------------------------------
#define SCALE16 0x7B7B7B7Bu   // e8m0 123 = 2^-4 in every byte

static __device__ __forceinline__ int8v ld_frag4(const uchar* rowp, int off) {
    uint4 u = *(const uint4*)(rowp + off);
    int8v v;
    v[0] = u.x; v[1] = u.y; v[2] = u.z; v[3] = u.w;
    v[4] = 0;   v[5] = 0;   v[6] = 0;   v[7] = 0;   // fp4 uses regs [0:3]
    return v;
}

__global__ __launch_bounds__(512, 4) void sim_max_kernel(const uchar* __restrict__ Q4,
                                                         const uchar* __restrict__ P4,
                                                         float* __restrict__ mv) {
    const int p  = blockIdx.x;   // 0..127  p-group
    const int qp = blockIdx.y;   // 0..7    q-pair (2 q-groups)
    __shared__ uchar lA[128 * 128];   // 16 KB
    __shared__ uchar lB[256 * 128];   // 32 KB
    __shared__ float smax[8];

    const int t = threadIdx.x;
    const int wave = t >> 6, lane = t & 63;
    const int qi = wave >> 2, pj = wave & 3;

    // DMA lane constants (8 rows x 128 B per instruction, XOR chunk swizzle)
    const int lrow = lane >> 3;                                // 0..7
    const int dmaoff = lrow * D2 + (((lane & 7) ^ lrow) << 4); // bytes

    // read lane constants
    const int r  = lane & 31;    // operand row within 32-tile
    const int kh = lane >> 5;    // k-half of the K=64 instruction
    const int rx = r & 7;

    const uchar* Abase = Q4 + (size_t)(qp * 128) * D2;
    const uchar* Bbase = P4 + (size_t)p * PJ * D2;

    floatx16 acc[2][2];
    #pragma unroll
    for (int i = 0; i < 2; i++)
        #pragma unroll
        for (int j = 0; j < 2; j++)
            #pragma unroll
            for (int e = 0; e < 16; e++) acc[i][j][e] = 0.f;

    for (int k0 = 0; k0 < D2; k0 += 128) {   // 3 mega-steps of K=256
        __syncthreads();   // previous readers done before DMA overwrites LDS
        #pragma unroll
        for (int g = 0; g < 2; g++) {   // A: 128 rows, wave stages [wave*16,+16)
            const int R0 = wave * 16 + g * 8;
            async_copy16(Abase + (size_t)R0 * D2 + k0 + dmaoff, lA + R0 * 128);
        }
        #pragma unroll
        for (int g = 0; g < 4; g++) {   // B: 256 rows, wave stages [wave*32,+32)
            const int R0 = wave * 32 + g * 8;
            async_copy16(Bbase + (size_t)R0 * D2 + k0 + dmaoff, lB + R0 * 128);
        }
        __syncthreads();   // vmcnt(0) drain: DMA visible to all waves

        #pragma unroll
        for (int s = 0; s < 4; s++) {   // four K=64 substeps per mega-step
            const int off = ((s * 2 + kh) ^ rx) << 4;
            int8v a[2];
            #pragma unroll
            for (int i = 0; i < 2; i++)
                a[i] = ld_frag4(lA + (qi * 64 + i * 32 + r) * 128, off);
            #pragma unroll
            for (int j = 0; j < 2; j++) {
                int8v b = ld_frag4(lB + (pj * 64 + j * 32 + r) * 128, off);
                #pragma unroll
                for (int i = 0; i < 2; i++)
                    acc[i][j] = __builtin_amdgcn_mfma_scale_f32_32x32x64_f8f6f4(
                        a[i], b, acc[i][j], 4, 4, 0, SCALE16, 0, SCALE16);
            }
        }
    }

    float m = -1e30f;
    #pragma unroll
    for (int i = 0; i < 2; i++)
        #pragma unroll
        for (int j = 0; j < 2; j++)
            #pragma unroll
            for (int e = 0; e < 16; e++) m = fmaxf(m, acc[i][j][e]);
    #pragma unroll
    for (int o = 32; o > 0; o >>= 1) m = fmaxf(m, __shfl_xor(m, o, 64));
    if (lane == 0) smax[wave] = m;
    __syncthreads();
    if (t < 2)   // q-group t: waves [t*4, t*4+4)
        mv[(qp * 2 + t) * NP + p] = fmaxf(fmaxf(smax[t*4], smax[t*4+1]),
                                          fmaxf(smax[t*4+2], smax[t*4+3]));
}

// ---------------------------------------------------------------------------
// Kernel 3: final loss. 16 waves — wave q handles row q (parallel, not a
// serial q-loop); lane covers columns {lane, lane+64}. Partials through LDS.
// loss = 0.5*(0.3*(CE_s + KLD_mv + CE_inter) + 0.2*(KLD_s + KLD_mv))
// (reference's CE(mv_scores) is dead code — overwritten by the KLD)
// ---------------------------------------------------------------------------
__global__ __launch_bounds__(1024) void loss_kernel(const float* __restrict__ scores,
                                                    const float* __restrict__ mv,
                                                    float* __restrict__ out) {
    const int q = threadIdx.x >> 6, lane = threadIdx.x & 63;
    __shared__ float part[4][16];

    const float* srow = scores + q * NP;
    const float* mrow = mv + q * NP;
    float s0 = srow[lane], s1 = srow[lane + 64];
    float m0 = mrow[lane], m1 = mrow[lane + 64];
    float t0 = s0 + 0.3f * m0, t1 = s1 + 0.3f * m1;

    float xs = fmaxf(s0, s1), xm = fmaxf(m0, m1), xt = fmaxf(t0, t1);
    #pragma unroll
    for (int o = 32; o > 0; o >>= 1) {
        xs = fmaxf(xs, __shfl_xor(xs, o, 64));
        xm = fmaxf(xm, __shfl_xor(xm, o, 64));
        xt = fmaxf(xt, __shfl_xor(xt, o, 64));
    }
    float es = expf(s0 - xs) + expf(s1 - xs);
    float em = expf(m0 - xm) + expf(m1 - xm);
    float et = expf(t0 - xt) + expf(t1 - xt);
    #pragma unroll
    for (int o = 32; o > 0; o >>= 1) {
        es += __shfl_xor(es, o, 64);
        em += __shfl_xor(em, o, 64);
        et += __shfl_xor(et, o, 64);
    }
    float lse_s = xs + logf(es), lse_m = xm + logf(em), lse_t = xt + logf(et);

    float ls0 = s0 - lse_s, ls1 = s1 - lse_s;
    float lm0 = m0 - lse_m, lm1 = m1 - lse_m;
    float lt0 = t0 - lse_t, lt1 = t1 - lse_t;
    float pt0 = expf(lt0), pt1 = expf(lt1);
    float kld_s = pt0 * (lt0 - ls0) + pt1 * (lt1 - ls1);
    float kld_m = pt0 * (lt0 - lm0) + pt1 * (lt1 - lm1);
    float ce_s = 0.f, ce_t = 0.f;

    const int tgt = q * (NP / NQ);     // q*8
    if (lane == (tgt & 63)) {
        if (tgt < 64) { ce_s = -ls0; ce_t = -lt0; }
        else          { ce_s = -ls1; ce_t = -lt1; }
    }
    #pragma unroll
    for (int o = 32; o > 0; o >>= 1) {
        ce_s  += __shfl_xor(ce_s, o, 64);
        ce_t  += __shfl_xor(ce_t, o, 64);
        kld_s += __shfl_xor(kld_s, o, 64);
        kld_m += __shfl_xor(kld_m, o, 64);
    }
    if (lane == 0) {
        part[0][q] = ce_s; part[1][q] = ce_t;
        part[2][q] = kld_s; part[3][q] = kld_m;
    }
    __syncthreads();
    if (threadIdx.x < 64) {
        float v0 = lane < 16 ? part[0][lane] : 0.f;
        float v1 = lane < 16 ? part[1][lane] : 0.f;
        float v2 = lane < 16 ? part[2][lane] : 0.f;
        float v3 = lane < 16 ? part[3][lane] : 0.f;
        #pragma unroll
        for (int o = 8; o > 0; o >>= 1) {
            v0 += __shfl_xor(v0, o, 64);
            v1 += __shfl_xor(v1, o, 64);
            v2 += __shfl_xor(v2, o, 64);
            v3 += __shfl_xor(v3, o, 64);
        }
        if (lane == 0) {
            v0 /= 16.f; v1 /= 16.f; v2 /= 16.f; v3 /= 16.f;
            float L1 = 0.3f * (v0 + v3 + v1);
            float L2 = 0.2f * (v2 + v3);
            out[0] = 0.5f * (L1 + L2);
        }
    }
}

// ---------------------------------------------------------------------------
extern "C" void kernel_launch(void* const* d_in, const int* in_sizes, int n_in,
                              void* d_out, int out_size, void* d_ws, size_t ws_size,
                              hipStream_t stream) {
    const float* qh = (const float*)d_in[0];   // (16, 64, 768) fp32
    const float* ph = (const float*)d_in[1];   // (128, 256, 768) fp32

    // workspace layout (~13 MB): P4 fp4 | Q4 fp4 | mv f32 | scores f32
    char* ws = (char*)d_ws;
    uchar* P4 = (uchar*)ws;
    uchar* Q4 = (uchar*)(ws + (size_t)MP * D2);
    float* mv = (float*)(ws + (size_t)MP * D2 + (size_t)MQ * D2);
    float* scores = mv + NQ * NP;

    norm_scores<<<NROWBLK + 512, 256, 0, stream>>>(ph, qh, P4, Q4, scores);
    sim_max_kernel<<<dim3(NP, 8), 512, 0, stream>>>(Q4, P4, mv);
    loss_kernel<<<1, 1024, 0, stream>>>(scores, mv, (float*)d_out);
}